// Round 6
// baseline (343.793 us; speedup 1.0000x reference)
//
#include <hip/hip_runtime.h>
#include <hip/hip_bf16.h>

// ---------------------------------------------------------------------------
// SelfAttention: QKV = X@W ; S = Q K^T / sqrt(512) ; P = softmax(S, axis=q) ;
// out = P @ V.   B=4, S=4096, D_IN=1024, A=512, O=1024.
// Softmax over the *q* axis (per key column).  Strategy: materialize
// P = exp(S) (unnormalized, bf16); fold 1/l into Vt; out = P @ Vt'.
// All GEMMs share a 256x256-tile, BK=64, 8-phase counted-vmcnt schedule.
// Operand order per kernel is chosen so the MFMA j-direction matches the
// output buffer's contiguous axis -> all epilogues are 8B uint2 stores.
// ---------------------------------------------------------------------------

typedef unsigned int u32;
typedef unsigned short u16;
typedef __bf16 bf16x8 __attribute__((ext_vector_type(8)));
typedef float f32x4 __attribute__((ext_vector_type(4)));
typedef u16 ushort8_t __attribute__((ext_vector_type(8)));

#define SCL 0.04419417382415922f   // 1/sqrt(512)

#define GLOAD16(gp, lp)                                                        \
  __builtin_amdgcn_global_load_lds(                                            \
      (const __attribute__((address_space(1))) u32*)(gp),                      \
      (__attribute__((address_space(3))) u32*)(lp), 16, 0, 0)

__device__ __forceinline__ u16 f2bf(float f) {
  union { float f; u32 u; } v; v.f = f;
  u32 r = (v.u + 0x7fffu + ((v.u >> 16) & 1u)) >> 16;   // RNE
  return (u16)r;
}
__device__ __forceinline__ float bf2f(u16 h) {
  union { u32 u; float f; } v; v.u = ((u32)h) << 16;
  return v.f;
}

// ---------------- K1: X fp32 -> bf16 -------------------------------------
__global__ __launch_bounds__(256) void k_cvt_x(const float* __restrict__ X,
                                               u16* __restrict__ Xb) {
  size_t i = ((size_t)blockIdx.x * 256 + threadIdx.x) * 8;
  const float4* p = (const float4*)(X + i);
  float4 a = p[0], b = p[1];
  ushort8_t o;
  o[0] = f2bf(a.x); o[1] = f2bf(a.y); o[2] = f2bf(a.z); o[3] = f2bf(a.w);
  o[4] = f2bf(b.x); o[5] = f2bf(b.y); o[6] = f2bf(b.z); o[7] = f2bf(b.w);
  *(ushort8_t*)(Xb + i) = o;
}

// ---------------- K2: W [1024][2048] fp32 -> Wbt [2048][1024] bf16 --------
__global__ __launch_bounds__(256) void k_cvt_w(const float* __restrict__ W,
                                               u16* __restrict__ Wbt) {
  __shared__ float t[64][65];
  const int e0 = blockIdx.x * 64, d0 = blockIdx.y * 64;
  const int c = threadIdx.x & 63, r4 = threadIdx.x >> 6;
#pragma unroll
  for (int i = 0; i < 16; i++) {
    int d = r4 + i * 4;
    t[d][c] = W[(size_t)(d0 + d) * 2048 + e0 + c];
  }
  __syncthreads();
#pragma unroll
  for (int i = 0; i < 16; i++) {
    int e = r4 + i * 4;
    Wbt[(size_t)(e0 + e) * 1024 + d0 + c] = f2bf(t[c][e]);
  }
}

// ---------------------------------------------------------------------------
// 8-phase GEMM body: C(256x256) = A(256xK) * B(256xK)^T, BK=64.
// LDS 128KB: A slots 0/1 @ 0/32KB (even/odd K-tiles), B slots @ 64/96KB.
// Slot = [256 rows][64 cols] bf16, 16B chunk c of row r holds global chunk
// c ^ (r&7)  (measured conflict-free).  8 waves (2 wr x 4 wc), per-wave
// C = 128x64 = acc[8][4].  acc[m][n][j]: A-row = wr*128+m*16+lg*4+j,
// B-row = wc*64+n*16+lr.
// ---------------------------------------------------------------------------
__device__ __forceinline__ void gemm8(const u16* __restrict__ Ab,
                                      const u16* __restrict__ Bb,
                                      int lda, int ldb, int NT,
                                      u16* lds, f32x4 (&acc)[8][4]) {
  const int tid = threadIdx.x;
  const int w = tid >> 6, l = tid & 63;
  const int lr = l & 15, lg = l >> 4;
  const int wr = w >> 2, wc = w & 3;

  const int gcs = (tid & 7) ^ ((tid >> 3) & 7);
  const u16* pA = Ab + (size_t)(tid >> 3) * lda + gcs * 8;
  const u16* pB = Bb + (size_t)(tid >> 3) * ldb + gcs * 8;

  const int ac0 = (lg ^ (lr & 7)) * 8;
  const int ac1 = ((4 + lg) ^ (lr & 7)) * 8;
  const int aoff = (wr * 128 + lr) * 64;
  const int boff = (wc * 64 + lr) * 64;

  bf16x8 bfrag[4][2];

  auto stA = [&](int kt, int R) {
    GLOAD16(pA + (size_t)R * lda + kt * 64,
            lds + ((kt & 1) << 14) + R * 64 + (w << 9));
  };
  auto stB = [&](int kt, int R) {
    GLOAD16(pB + (size_t)R * ldb + kt * 64,
            lds + 32768 + ((kt & 1) << 14) + R * 64 + (w << 9));
  };

  auto phase = [&](int qd, int asl, bool loadB, int bsl, auto&& stagefn,
                   int ckpt) {
    if (loadB) {
#pragma unroll
      for (int n = 0; n < 4; n++) {
        bfrag[n][0] = *(const bf16x8*)&lds[32768 + (bsl << 14) + boff + n * 1024 + ac0];
        bfrag[n][1] = *(const bf16x8*)&lds[32768 + (bsl << 14) + boff + n * 1024 + ac1];
      }
    }
    bf16x8 a[2][2];
#pragma unroll
    for (int m2 = 0; m2 < 2; m2++) {
      a[m2][0] = *(const bf16x8*)&lds[(asl << 14) + aoff + qd * 2048 + m2 * 1024 + ac0];
      a[m2][1] = *(const bf16x8*)&lds[(asl << 14) + aoff + qd * 2048 + m2 * 1024 + ac1];
    }
    stagefn();
    if (loadB) asm volatile("s_waitcnt lgkmcnt(8)" ::: "memory");
    __builtin_amdgcn_s_barrier();
    asm volatile("s_waitcnt lgkmcnt(0)" ::: "memory");
    __builtin_amdgcn_sched_barrier(0);
    __builtin_amdgcn_s_setprio(1);
#pragma unroll
    for (int m2 = 0; m2 < 2; m2++)
#pragma unroll
      for (int n = 0; n < 4; n++)
#pragma unroll
        for (int kk = 0; kk < 2; kk++)
          acc[qd * 2 + m2][n] = __builtin_amdgcn_mfma_f32_16x16x32_bf16(
              a[m2][kk], bfrag[n][kk], acc[qd * 2 + m2][n], 0, 0, 0);
    __builtin_amdgcn_s_setprio(0);
    if (ckpt == 6) asm volatile("s_waitcnt vmcnt(6)" ::: "memory");
    else if (ckpt == 0) asm volatile("s_waitcnt vmcnt(0)" ::: "memory");
    __builtin_amdgcn_s_barrier();
    __builtin_amdgcn_sched_barrier(0);
  };
  auto nostage = [&] {};

  // prologue: B(0), A(0)E, A(0)L, B(1), A(1)E  (14 issues); drain to 6.
  stB(0, 0); stB(0, 64); stB(0, 128); stB(0, 192);
  stA(0, 0); stA(0, 128);
  stA(0, 64); stA(0, 192);
  stB(1, 0); stB(1, 64); stB(1, 128); stB(1, 192);
  stA(1, 0); stA(1, 128);
  asm volatile("s_waitcnt vmcnt(6)" ::: "memory");
  __builtin_amdgcn_s_barrier();
  __builtin_amdgcn_sched_barrier(0);

  const int NI = NT >> 1;
  for (int i = 0; i < NI - 1; i++) {
    const int kt = 2 * i;
    phase(0, 0, true , 0, [&] { stA(kt + 1, 64); stA(kt + 1, 192); }, -1);
    phase(1, 0, false, 0, [&] { stB(kt + 2, 0);  stB(kt + 2, 64);  }, -1);
    phase(2, 0, false, 0, [&] { stB(kt + 2, 128); stB(kt + 2, 192); }, -1);
    phase(3, 0, false, 0, [&] { stA(kt + 2, 0);  stA(kt + 2, 128); }, 6);
    phase(0, 1, true , 1, [&] { stA(kt + 2, 64); stA(kt + 2, 192); }, -1);
    phase(1, 1, false, 1, [&] { stB(kt + 3, 0);  stB(kt + 3, 64);  }, -1);
    phase(2, 1, false, 1, [&] { stB(kt + 3, 128); stB(kt + 3, 192); }, -1);
    phase(3, 1, false, 1, [&] { stA(kt + 3, 0);  stA(kt + 3, 128); }, 6);
  }
  {
    const int kt = 2 * (NI - 1);
    phase(0, 0, true , 0, [&] { stA(kt + 1, 64); stA(kt + 1, 192); }, -1);
    phase(1, 0, false, 0, nostage, -1);
    phase(2, 0, false, 0, nostage, -1);
    phase(3, 0, false, 0, nostage, 0);
    phase(0, 1, true , 1, nostage, -1);
    phase(1, 1, false, 1, nostage, -1);
    phase(2, 1, false, 1, nostage, -1);
    phase(3, 1, false, 1, nostage, -1);
  }
}

// ---------------- K3: QKV GEMM (8-phase, 256x256, region-split) ------------
// h=0 blocks (e<1024): acc = C^T (rows=e, cols=s) -> QK[s][e] 8B stores.
// h=1 blocks (e>=1024): acc = C (rows=s, cols=o)  -> Vt[o][s] 8B stores.
__global__ __launch_bounds__(512, 2) void k_qkv(const u16* __restrict__ Xb,
                                                const u16* __restrict__ Wbt,
                                                u16* __restrict__ QK,
                                                u16* __restrict__ Vt) {
  __shared__ u16 lds[65536];
  const int cpx = 64;                    // nwg=512, XCD owns one (h,ci4) panel
  const int swz = ((int)blockIdx.x & 7) * cpx + ((int)blockIdx.x >> 3);
  const int ri = swz & 63, ci4 = (swz >> 6) & 3, h = swz >> 8;
  const int tid = threadIdx.x;
  const int w = tid >> 6, l = tid & 63;
  const int lr = l & 15, lg = l >> 4;
  const int wr = w >> 2, wc = w & 3;
  f32x4 acc[8][4] = {};
  const int bb = ri >> 4;
  if (h == 0) {
    gemm8(Wbt + (size_t)(ci4 * 256) * 1024, Xb + (size_t)(ri * 256) * 1024,
          1024, 1024, 16, lds, acc);
    const int sbase = (ri * 256) & 4095;
#pragma unroll
    for (int m = 0; m < 8; m++) {
      int e0 = ci4 * 256 + wr * 128 + m * 16 + lg * 4;
#pragma unroll
      for (int n = 0; n < 4; n++) {
        int s = sbase + wc * 64 + n * 16 + lr;
        f32x4 v = acc[m][n];
        u16 pk[4] = { f2bf(v[0]), f2bf(v[1]), f2bf(v[2]), f2bf(v[3]) };
        *(uint2*)&QK[((size_t)bb * 4096 + s) * 1024 + e0] = *(uint2*)pk;
      }
    }
  } else {
    gemm8(Xb + (size_t)(ri * 256) * 1024,
          Wbt + (size_t)(1024 + ci4 * 256) * 1024, 1024, 1024, 16, lds, acc);
    const int s0 = ((ri * 256) & 4095) + wr * 128;
#pragma unroll
    for (int m = 0; m < 8; m++) {
      int sb = s0 + m * 16 + lg * 4;
#pragma unroll
      for (int n = 0; n < 4; n++) {
        int o = ci4 * 256 + wc * 64 + n * 16 + lr;
        f32x4 v = acc[m][n];
        u16 pk[4] = { f2bf(v[0]), f2bf(v[1]), f2bf(v[2]), f2bf(v[3]) };
        *(uint2*)&Vt[((size_t)bb * 1024 + o) * 4096 + sb] = *(uint2*)pk;
      }
    }
  }
}

// ---------------- K4: S^T-GEMM + exp -> P, column sums (8-phase) -----------
// acc = S^T tile (rows=k, cols=q).  Per lane j spans 4 consecutive k ->
// P[q][k] written as 8B uint2.  Column sums (over q) = row sums here:
// in-register over n + shfl_xor over lr + tiny LDS cross-wave pass.
__global__ __launch_bounds__(512, 2) void k_sp(const u16* __restrict__ QK,
                                               u16* __restrict__ P,
                                               float* __restrict__ part,
                                               int b0, int nwg) {
  __shared__ u16 lds[65536];
  const int cpx = nwg >> 3;
  const int swz = ((int)blockIdx.x & 7) * cpx + ((int)blockIdx.x >> 3);
  const int qi = swz & 15, ki = (swz >> 4) & 15, bl = swz >> 8;
  const int b = b0 + bl;
  const int q0 = qi * 256, kk0 = ki * 256;

  f32x4 acc[8][4] = {};
  gemm8(QK + ((size_t)b * 4096 + kk0) * 1024 + 512,   // A = K rows
        QK + ((size_t)b * 4096 + q0) * 1024,          // B = Q rows
        1024, 1024, 8, lds, acc);

  const int tid = threadIdx.x;
  const int w = tid >> 6, l = tid & 63;
  const int lr = l & 15, lg = l >> 4;
  const int wr = w >> 2, wc = w & 3;

  float ps[8][4];
#pragma unroll
  for (int m = 0; m < 8; m++)
#pragma unroll
    for (int j = 0; j < 4; j++) ps[m][j] = 0.f;
#pragma unroll
  for (int m = 0; m < 8; m++)
#pragma unroll
    for (int n = 0; n < 4; n++)
#pragma unroll
      for (int j = 0; j < 4; j++) {
        float p = __expf(acc[m][n][j] * SCL);
        acc[m][n][j] = p;
        ps[m][j] += p;
      }
#pragma unroll
  for (int m = 0; m < 8; m++)
#pragma unroll
    for (int j = 0; j < 4; j++) {
      ps[m][j] += __shfl_xor(ps[m][j], 1);
      ps[m][j] += __shfl_xor(ps[m][j], 2);
      ps[m][j] += __shfl_xor(ps[m][j], 4);
      ps[m][j] += __shfl_xor(ps[m][j], 8);
    }
  __syncthreads();                       // gemm8 done; reuse lds as red[]
  float (*red)[4][128] = (float (*)[4][128])lds;
  if ((l & 15) == 0) {
#pragma unroll
    for (int m = 0; m < 8; m++)
#pragma unroll
      for (int j = 0; j < 4; j++)
        red[wr][wc][m * 16 + lg * 4 + j] = ps[m][j];
  }
  __syncthreads();
  if (tid < 256) {
    int k7 = tid & 127;
    float s = red[tid >> 7][0][k7] + red[tid >> 7][1][k7] +
              red[tid >> 7][2][k7] + red[tid >> 7][3][k7];
    part[((size_t)(bl * 16 + qi)) * 4096 + kk0 + tid] = s;
  }

  // direct P[q][k] write, 8B per (m,n)
#pragma unroll
  for (int m = 0; m < 8; m++) {
    int kc = kk0 + wr * 128 + m * 16 + lg * 4;
#pragma unroll
    for (int n = 0; n < 4; n++) {
      int q = q0 + wc * 64 + n * 16 + lr;
      f32x4 v = acc[m][n];
      u16 pk[4] = { f2bf(v[0]), f2bf(v[1]), f2bf(v[2]), f2bf(v[3]) };
      *(uint2*)&P[((size_t)bl * 4096 + q) * 4096 + kc] = *(uint2*)pk;
    }
  }
}

// ---------------- K5: linv[bl][k] = 1 / sum_qi part[bl][qi][k] -------------
__global__ __launch_bounds__(256) void k_finl(const float* __restrict__ part,
                                              float* __restrict__ linv) {
  int t = blockIdx.x * 256 + threadIdx.x;   // t < G*4096
  int bl = t >> 12, k = t & 4095;
  float s = 0.f;
#pragma unroll
  for (int qb = 0; qb < 16; qb++)
    s += part[((size_t)(bl * 16 + qb)) * 4096 + k];
  linv[t] = 1.0f / s;
}

// ---------------- K6: Vt[bl][o][k] *= linv[bl][k] -------------------------
__global__ __launch_bounds__(256) void k_scale(u16* __restrict__ Vtg,
                                               const float* __restrict__ linv) {
  size_t i = ((size_t)blockIdx.x * 256 + threadIdx.x) * 8;
  int bl = (int)(i >> 22);
  int k = (int)(i & 4095);
  const float* lp = linv + ((size_t)bl << 12) + k;
  ushort8_t v = *(ushort8_t*)(Vtg + i);
#pragma unroll
  for (int j = 0; j < 8; j++) v[j] = f2bf(bf2f(v[j]) * lp[j]);
  *(ushort8_t*)(Vtg + i) = v;
}

// ---------------- K7: out = P @ Vt'  (8-phase, 256x256) --------------------
__global__ __launch_bounds__(512, 2) void k_pv(const u16* __restrict__ P,
                                               const u16* __restrict__ Vtg,
                                               float* __restrict__ outg,
                                               int nwg) {
  __shared__ u16 lds[65536];
  const int cpx = nwg >> 3;
  const int swz = ((int)blockIdx.x & 7) * cpx + ((int)blockIdx.x >> 3);
  const int qi = swz & 15, oi = (swz >> 4) & 3, bl = swz >> 6;
  const int q0 = qi * 256, o0 = oi * 256;

  f32x4 acc[8][4] = {};
  gemm8(P + ((size_t)bl * 4096 + q0) * 4096,
        Vtg + ((size_t)bl * 1024 + o0) * 4096, 4096, 4096, 64, lds, acc);

  const int tid = threadIdx.x;
  const int w = tid >> 6, l = tid & 63;
  const int lr = l & 15, lg = l >> 4;
  const int wr = w >> 2, wc = w & 3;
#pragma unroll
  for (int m = 0; m < 8; m++) {
    int q = q0 + wr * 128 + m * 16 + lg * 4;
#pragma unroll
    for (int n = 0; n < 4; n++) {
      int o = o0 + wc * 64 + n * 16 + lr;
      f32x4 v = acc[m][n];
#pragma unroll
      for (int j = 0; j < 4; j++)
        outg[((size_t)bl * 4096 + q + j) * 1024 + o] = v[j];
    }
  }
}

// ---------------------------------------------------------------------------
extern "C" void kernel_launch(void* const* d_in, const int* in_sizes, int n_in,
                              void* d_out, int out_size, void* d_ws, size_t ws_size,
                              hipStream_t stream) {
  const float* X = (const float*)d_in[0];   // 4*4096*1024
  const float* W = (const float*)d_in[1];   // 1024*2048
  float* out = (float*)d_out;               // 4*4096*1024 fp32
  char* ws = (char*)d_ws;

  int G;
  if (ws_size >= 203489280ull)      G = 4;
  else if (ws_size >= 135299072ull) G = 2;
  else if (ws_size >= 104857600ull) G = 1;
  else return;
  const size_t PB = (size_t)G * 33554432ull;

  // layout (bytes):
  //   QK @ 0          (32MB)   bf16 [4][4096][1024]  (cols 0-511 Q, 512-1023 K)
  //   Vt @ 32MB       (32MB)   bf16 [4][1024][4096]
  //   P  @ 64MB       (PB)     bf16 [G][4096][4096]
  //   Xb @ 64MB       (32MB)   aliases P (dead after k_qkv)
  //   Wbt@ 96MB       (4MB)    aliases P (dead after k_qkv)
  //   part @ 64MB+PB  (G*256KB) f32 [G][16][4096]
  //   linv @ +part    (G*16KB)  f32 [G][4096]
  u16* QK  = (u16*)(ws);
  u16* Vt  = (u16*)(ws + 33554432);
  u16* P   = (u16*)(ws + 67108864);
  u16* Xb  = (u16*)(ws + 67108864);
  u16* Wbt = (u16*)(ws + 100663296);
  float* part = (float*)(ws + 67108864 + PB);
  float* linv = (float*)(ws + 67108864 + PB + (size_t)G * 262144ull);

  k_cvt_x<<<dim3(8192), dim3(256), 0, stream>>>(X, Xb);
  k_cvt_w<<<dim3(32, 16), dim3(256), 0, stream>>>(W, Wbt);
  k_qkv<<<dim3(512), dim3(512), 0, stream>>>(Xb, Wbt, QK, Vt);
  for (int b0 = 0; b0 < 4; b0 += G) {
    int nwg_sp = 256 * G;
    k_sp<<<dim3(nwg_sp), dim3(512), 0, stream>>>(QK, P, part, b0, nwg_sp);
    k_finl<<<dim3(G * 16), dim3(256), 0, stream>>>(part, linv);
    k_scale<<<dim3(G * 2048), dim3(256), 0, stream>>>(Vt + (size_t)b0 * 4194304, linv);
    int nwg = 64 * G;
    k_pv<<<dim3(nwg), dim3(512), 0, stream>>>(P, Vt + (size_t)b0 * 4194304,
                                              out + (size_t)b0 * 4194304, nwg);
  }
}

// Round 7
// 318.469 us; speedup vs baseline: 1.0795x; 1.0795x over previous
//
#include <hip/hip_runtime.h>
#include <hip/hip_bf16.h>

// ---------------------------------------------------------------------------
// SelfAttention: QKV = X@W ; S = Q K^T / sqrt(512) ; P = softmax(S, axis=q) ;
// out = P @ V.   B=4, S=4096, D_IN=1024, A=512, O=1024.
// Softmax over the *q* axis (per key column).  Materialize P = exp(S)
// (unnormalized bf16, TILED layout [bl][ki][q][256]); fold 1/l into Vt;
// out = P @ Vt'.  All GEMMs: 256x256 tile, BK=64, 8-phase counted-vmcnt.
// Epilogues use a pair-shfl regroup so every store is a 16B uint4 and each
// 4-lane group covers 64B contiguous (full sector).
// ---------------------------------------------------------------------------

typedef unsigned int u32;
typedef unsigned short u16;
typedef __bf16 bf16x8 __attribute__((ext_vector_type(8)));
typedef float f32x4 __attribute__((ext_vector_type(4)));
typedef u16 ushort8_t __attribute__((ext_vector_type(8)));

#define SCL 0.04419417382415922f   // 1/sqrt(512)

#define GLOAD16(gp, lp)                                                        \
  __builtin_amdgcn_global_load_lds(                                            \
      (const __attribute__((address_space(1))) u32*)(gp),                      \
      (__attribute__((address_space(3))) u32*)(lp), 16, 0, 0)

__device__ __forceinline__ u16 f2bf(float f) {
  union { float f; u32 u; } v; v.f = f;
  u32 r = (v.u + 0x7fffu + ((v.u >> 16) & 1u)) >> 16;   // RNE
  return (u16)r;
}
__device__ __forceinline__ float bf2f(u16 h) {
  union { u32 u; float f; } v; v.u = ((u32)h) << 16;
  return v.f;
}

// ---------------- K1: X fp32 -> bf16 -------------------------------------
__global__ __launch_bounds__(256) void k_cvt_x(const float* __restrict__ X,
                                               u16* __restrict__ Xb) {
  size_t i = ((size_t)blockIdx.x * 256 + threadIdx.x) * 8;
  const float4* p = (const float4*)(X + i);
  float4 a = p[0], b = p[1];
  ushort8_t o;
  o[0] = f2bf(a.x); o[1] = f2bf(a.y); o[2] = f2bf(a.z); o[3] = f2bf(a.w);
  o[4] = f2bf(b.x); o[5] = f2bf(b.y); o[6] = f2bf(b.z); o[7] = f2bf(b.w);
  *(ushort8_t*)(Xb + i) = o;
}

// ---------------- K2: W [1024][2048] fp32 -> Wbt [2048][1024] bf16 --------
__global__ __launch_bounds__(256) void k_cvt_w(const float* __restrict__ W,
                                               u16* __restrict__ Wbt) {
  __shared__ float t[64][65];
  const int e0 = blockIdx.x * 64, d0 = blockIdx.y * 64;
  const int c = threadIdx.x & 63, r4 = threadIdx.x >> 6;
#pragma unroll
  for (int i = 0; i < 16; i++) {
    int d = r4 + i * 4;
    t[d][c] = W[(size_t)(d0 + d) * 2048 + e0 + c];
  }
  __syncthreads();
#pragma unroll
  for (int i = 0; i < 16; i++) {
    int e = r4 + i * 4;
    Wbt[(size_t)(e0 + e) * 1024 + d0 + c] = f2bf(t[c][e]);
  }
}

// ---------------------------------------------------------------------------
// Pair-shfl regroup store: acc[8][4] (rows j-contig along cols of `colbase`
// axis, 16 rows via lr on the `rowbase` axis).  Lanes {lg,lg^1} exchange 8B
// so each lane stores one 16B uint4; a 4-lane lg-group covers 64B contiguous.
// ---------------------------------------------------------------------------
__device__ __forceinline__ void rg_store(const f32x4 (&acc)[8][4],
                                         u16* __restrict__ base, int rowbase,
                                         int rstride, int colbase) {
  const int l = threadIdx.x & 63;
  const int lr = l & 15, lg = l >> 4;
  const int sel = lg & 1, hi = lg >> 1;
#pragma unroll
  for (int mg = 0; mg < 4; mg++) {
#pragma unroll
    for (int n = 0; n < 4; n++) {
      f32x4 ve = acc[2 * mg][n], vo = acc[2 * mg + 1][n];
      u32 e0 = (u32)f2bf(ve[0]) | ((u32)f2bf(ve[1]) << 16);
      u32 e1 = (u32)f2bf(ve[2]) | ((u32)f2bf(ve[3]) << 16);
      u32 o0 = (u32)f2bf(vo[0]) | ((u32)f2bf(vo[1]) << 16);
      u32 o1 = (u32)f2bf(vo[2]) | ((u32)f2bf(vo[3]) << 16);
      u32 ex0 = (u32)__shfl_xor((int)e0, 16);
      u32 ex1 = (u32)__shfl_xor((int)e1, 16);
      u32 ox0 = (u32)__shfl_xor((int)o0, 16);
      u32 ox1 = (u32)__shfl_xor((int)o1, 16);
      uint4 v;
      v.x = sel ? ox0 : e0;
      v.y = sel ? ox1 : e1;
      v.z = sel ? o0 : ex0;
      v.w = sel ? o1 : ex1;
      int col = colbase + mg * 32 + sel * 16 + hi * 8;
      *(uint4*)&base[(size_t)(rowbase + n * 16 + lr) * rstride + col] = v;
    }
  }
}

// ---------------------------------------------------------------------------
// 8-phase GEMM body: C(256x256) = A(256xK) * B(256xK)^T, BK=64.
// AM=0: A rows linear stride lda.  AM=1: A = tiled-P [ki][4096][256]
// (row stride 256, kt offset = (kt>>2)<<20 | (kt&3)<<6).
// LDS 128KB: A slots @0/32KB, B slots @64/96KB; 16B chunk c of row r holds
// global chunk c^(r&7) (measured conflict-free).
// ---------------------------------------------------------------------------
template <int AM>
__device__ __forceinline__ void gemm8(const u16* __restrict__ Ab,
                                      const u16* __restrict__ Bb,
                                      int lda, int ldb, int NT,
                                      u16* lds, f32x4 (&acc)[8][4]) {
  const int tid = threadIdx.x;
  const int w = tid >> 6, l = tid & 63;
  const int lr = l & 15, lg = l >> 4;
  const int wr = w >> 2, wc = w & 3;

  const int gcs = (tid & 7) ^ ((tid >> 3) & 7);
  const u16* pA = Ab + (size_t)(tid >> 3) * lda + gcs * 8;
  const u16* pB = Bb + (size_t)(tid >> 3) * ldb + gcs * 8;

  const int ac0 = (lg ^ (lr & 7)) * 8;
  const int ac1 = ((4 + lg) ^ (lr & 7)) * 8;
  const int aoff = (wr * 128 + lr) * 64;
  const int boff = (wc * 64 + lr) * 64;

  bf16x8 bfrag[4][2];

  auto stA = [&](int kt, int R) {
    size_t ko = (AM == 1) ? (size_t)(((kt >> 2) << 20) | ((kt & 3) << 6))
                          : (size_t)kt * 64;
    GLOAD16(pA + (size_t)R * lda + ko,
            lds + ((kt & 1) << 14) + R * 64 + (w << 9));
  };
  auto stB = [&](int kt, int R) {
    GLOAD16(pB + (size_t)R * ldb + (size_t)kt * 64,
            lds + 32768 + ((kt & 1) << 14) + R * 64 + (w << 9));
  };

  auto phase = [&](int qd, int asl, bool loadB, int bsl, auto&& stagefn,
                   int ckpt) {
    if (loadB) {
#pragma unroll
      for (int n = 0; n < 4; n++) {
        bfrag[n][0] = *(const bf16x8*)&lds[32768 + (bsl << 14) + boff + n * 1024 + ac0];
        bfrag[n][1] = *(const bf16x8*)&lds[32768 + (bsl << 14) + boff + n * 1024 + ac1];
      }
    }
    bf16x8 a[2][2];
#pragma unroll
    for (int m2 = 0; m2 < 2; m2++) {
      a[m2][0] = *(const bf16x8*)&lds[(asl << 14) + aoff + qd * 2048 + m2 * 1024 + ac0];
      a[m2][1] = *(const bf16x8*)&lds[(asl << 14) + aoff + qd * 2048 + m2 * 1024 + ac1];
    }
    stagefn();
    if (loadB) asm volatile("s_waitcnt lgkmcnt(8)" ::: "memory");
    __builtin_amdgcn_s_barrier();
    asm volatile("s_waitcnt lgkmcnt(0)" ::: "memory");
    __builtin_amdgcn_sched_barrier(0);
    __builtin_amdgcn_s_setprio(1);
#pragma unroll
    for (int m2 = 0; m2 < 2; m2++)
#pragma unroll
      for (int n = 0; n < 4; n++)
#pragma unroll
        for (int kk = 0; kk < 2; kk++)
          acc[qd * 2 + m2][n] = __builtin_amdgcn_mfma_f32_16x16x32_bf16(
              a[m2][kk], bfrag[n][kk], acc[qd * 2 + m2][n], 0, 0, 0);
    __builtin_amdgcn_s_setprio(0);
    if (ckpt == 6) asm volatile("s_waitcnt vmcnt(6)" ::: "memory");
    else if (ckpt == 0) asm volatile("s_waitcnt vmcnt(0)" ::: "memory");
    __builtin_amdgcn_s_barrier();
    __builtin_amdgcn_sched_barrier(0);
  };
  auto nostage = [&] {};

  // prologue: B(0), A(0)E, A(0)L, B(1), A(1)E  (14 issues); drain to 6.
  stB(0, 0); stB(0, 64); stB(0, 128); stB(0, 192);
  stA(0, 0); stA(0, 128);
  stA(0, 64); stA(0, 192);
  stB(1, 0); stB(1, 64); stB(1, 128); stB(1, 192);
  stA(1, 0); stA(1, 128);
  asm volatile("s_waitcnt vmcnt(6)" ::: "memory");
  __builtin_amdgcn_s_barrier();
  __builtin_amdgcn_sched_barrier(0);

  const int NI = NT >> 1;
  for (int i = 0; i < NI - 1; i++) {
    const int kt = 2 * i;
    phase(0, 0, true , 0, [&] { stA(kt + 1, 64); stA(kt + 1, 192); }, -1);
    phase(1, 0, false, 0, [&] { stB(kt + 2, 0);  stB(kt + 2, 64);  }, -1);
    phase(2, 0, false, 0, [&] { stB(kt + 2, 128); stB(kt + 2, 192); }, -1);
    phase(3, 0, false, 0, [&] { stA(kt + 2, 0);  stA(kt + 2, 128); }, 6);
    phase(0, 1, true , 1, [&] { stA(kt + 2, 64); stA(kt + 2, 192); }, -1);
    phase(1, 1, false, 1, [&] { stB(kt + 3, 0);  stB(kt + 3, 64);  }, -1);
    phase(2, 1, false, 1, [&] { stB(kt + 3, 128); stB(kt + 3, 192); }, -1);
    phase(3, 1, false, 1, [&] { stA(kt + 3, 0);  stA(kt + 3, 128); }, 6);
  }
  {
    const int kt = 2 * (NI - 1);
    phase(0, 0, true , 0, [&] { stA(kt + 1, 64); stA(kt + 1, 192); }, -1);
    phase(1, 0, false, 0, nostage, -1);
    phase(2, 0, false, 0, nostage, -1);
    phase(3, 0, false, 0, nostage, 0);
    phase(0, 1, true , 1, nostage, -1);
    phase(1, 1, false, 1, nostage, -1);
    phase(2, 1, false, 1, nostage, -1);
    phase(3, 1, false, 1, nostage, -1);
  }
}

// ---------------- K3: QKV GEMM (8-phase, 256x256, region-split) ------------
// h=0 (e<1024): acc = C^T (j-dir = e) -> QK[s][e].  h=1: acc = C (j-dir = s)
// -> Vt[o][s].  Both stores via rg_store (64B-coalesced).
// Decode: X-row panel inner so 8 blocks sharing one X panel land on one XCD.
__global__ __launch_bounds__(512, 2) void k_qkv(const u16* __restrict__ Xb,
                                                const u16* __restrict__ Wbt,
                                                u16* __restrict__ QK,
                                                u16* __restrict__ Vt) {
  __shared__ u16 lds[65536];
  const int cpx = 64;                    // nwg = 512
  const int swz = ((int)blockIdx.x & 7) * cpx + ((int)blockIdx.x >> 3);
  const int c8 = swz & 7, ri = swz >> 3;
  const int ci4 = c8 & 3, h = c8 >> 2;
  const int tid = threadIdx.x;
  const int w = tid >> 6;
  const int wr = w >> 2, wc = w & 3;
  f32x4 acc[8][4] = {};
  const int bb = ri >> 4;
  const int sbase = (ri * 256) & 4095;
  if (h == 0) {
    gemm8<0>(Wbt + (size_t)(ci4 * 256) * 1024, Xb + (size_t)(ri * 256) * 1024,
             1024, 1024, 16, lds, acc);
    rg_store(acc, QK + (size_t)bb * 4096 * 1024,
             sbase + wc * 64, 1024, ci4 * 256 + wr * 128);
  } else {
    gemm8<0>(Xb + (size_t)(ri * 256) * 1024,
             Wbt + (size_t)(1024 + ci4 * 256) * 1024, 1024, 1024, 16, lds, acc);
    rg_store(acc, Vt + (size_t)bb * 1024 * 4096,
             ci4 * 256 + wc * 64, 4096, sbase + wr * 128);
  }
}

// ---------------- K4: S^T-GEMM + exp -> tiled P, column sums ---------------
// acc = S^T tile (A = K rows, j-dir = k; B = Q rows via lr).  Column sums
// (over q) are row sums: in-reg over n + shfl over lr + LDS cross-wave pass.
// P written tiled [bl][ki][q][256] via rg_store (64B-coalesced).
// Decode: ki inner -> one XCD's concurrent blocks share a Q panel (L2-hot).
__global__ __launch_bounds__(512, 2) void k_sp(const u16* __restrict__ QK,
                                               u16* __restrict__ P,
                                               float* __restrict__ part,
                                               int b0, int nwg) {
  __shared__ u16 lds[65536];
  const int cpx = nwg >> 3;
  const int swz = ((int)blockIdx.x & 7) * cpx + ((int)blockIdx.x >> 3);
  const int ki = swz & 15, qi = (swz >> 4) & 15, bl = swz >> 8;
  const int b = b0 + bl;
  const int q0 = qi * 256;

  f32x4 acc[8][4] = {};
  gemm8<0>(QK + ((size_t)b * 4096 + ki * 256) * 1024 + 512,  // A = K rows
           QK + ((size_t)b * 4096 + q0) * 1024,              // B = Q rows
           1024, 1024, 8, lds, acc);

  const int tid = threadIdx.x;
  const int w = tid >> 6, l = tid & 63;
  const int lr = l & 15, lg = l >> 4;
  const int wr = w >> 2, wc = w & 3;

  float ps[8][4];
#pragma unroll
  for (int m = 0; m < 8; m++)
#pragma unroll
    for (int j = 0; j < 4; j++) ps[m][j] = 0.f;
#pragma unroll
  for (int m = 0; m < 8; m++)
#pragma unroll
    for (int n = 0; n < 4; n++)
#pragma unroll
      for (int j = 0; j < 4; j++) {
        float p = __expf(acc[m][n][j] * SCL);
        acc[m][n][j] = p;
        ps[m][j] += p;
      }

  // tiled-P store (no LDS, no barriers)
  rg_store(acc, P + (size_t)bl * 16777216 + (size_t)ki * 1048576,
           q0 + wc * 64, 256, wr * 128);

#pragma unroll
  for (int m = 0; m < 8; m++)
#pragma unroll
    for (int j = 0; j < 4; j++) {
      ps[m][j] += __shfl_xor(ps[m][j], 1);
      ps[m][j] += __shfl_xor(ps[m][j], 2);
      ps[m][j] += __shfl_xor(ps[m][j], 4);
      ps[m][j] += __shfl_xor(ps[m][j], 8);
    }
  __syncthreads();                       // gemm8 done; reuse lds as red[]
  float (*red)[4][128] = (float (*)[4][128])lds;
  if ((l & 15) == 0) {
#pragma unroll
    for (int m = 0; m < 8; m++)
#pragma unroll
      for (int j = 0; j < 4; j++)
        red[wr][wc][m * 16 + lg * 4 + j] = ps[m][j];
  }
  __syncthreads();
  if (tid < 256) {
    int k7 = tid & 127;
    float s = red[tid >> 7][0][k7] + red[tid >> 7][1][k7] +
              red[tid >> 7][2][k7] + red[tid >> 7][3][k7];
    part[((size_t)(bl * 16 + qi)) * 4096 + ki * 256 + tid] = s;
  }
}

// ---------------- K5: linv[bl][k] = 1 / sum_qi part[bl][qi][k] -------------
__global__ __launch_bounds__(256) void k_finl(const float* __restrict__ part,
                                              float* __restrict__ linv) {
  int t = blockIdx.x * 256 + threadIdx.x;   // t < G*4096
  int bl = t >> 12, k = t & 4095;
  float s = 0.f;
#pragma unroll
  for (int qb = 0; qb < 16; qb++)
    s += part[((size_t)(bl * 16 + qb)) * 4096 + k];
  linv[t] = 1.0f / s;
}

// ---------------- K6: Vt[bl][o][k] *= linv[bl][k] -------------------------
__global__ __launch_bounds__(256) void k_scale(u16* __restrict__ Vtg,
                                               const float* __restrict__ linv) {
  size_t i = ((size_t)blockIdx.x * 256 + threadIdx.x) * 8;
  int bl = (int)(i >> 22);
  int k = (int)(i & 4095);
  const float* lp = linv + ((size_t)bl << 12) + k;
  ushort8_t v = *(ushort8_t*)(Vtg + i);
#pragma unroll
  for (int j = 0; j < 8; j++) v[j] = f2bf(bf2f(v[j]) * lp[j]);
  *(ushort8_t*)(Vtg + i) = v;
}

// ---------------- K7: out = P(tiled) @ Vt'  (8-phase, 256x256) -------------
// Decode: oi inner -> 4 blocks sharing one P panel land on one XCD (L2-hot).
__global__ __launch_bounds__(512, 2) void k_pv(const u16* __restrict__ P,
                                               const u16* __restrict__ Vtg,
                                               float* __restrict__ outg,
                                               int nwg) {
  __shared__ u16 lds[65536];
  const int cpx = nwg >> 3;
  const int swz = ((int)blockIdx.x & 7) * cpx + ((int)blockIdx.x >> 3);
  const int oi = swz & 3, qi = (swz >> 2) & 15, bl = swz >> 6;
  const int q0 = qi * 256, o0 = oi * 256;

  f32x4 acc[8][4] = {};
  gemm8<1>(P + (size_t)bl * 16777216 + (size_t)q0 * 256,
           Vtg + ((size_t)bl * 1024 + o0) * 4096, 256, 4096, 64, lds, acc);

  const int tid = threadIdx.x;
  const int w = tid >> 6, l = tid & 63;
  const int lr = l & 15, lg = l >> 4;
  const int wr = w >> 2, wc = w & 3;
#pragma unroll
  for (int m = 0; m < 8; m++) {
    int q = q0 + wr * 128 + m * 16 + lg * 4;
#pragma unroll
    for (int n = 0; n < 4; n++) {
      int o = o0 + wc * 64 + n * 16 + lr;
      f32x4 v = acc[m][n];
#pragma unroll
      for (int j = 0; j < 4; j++)
        outg[((size_t)bl * 4096 + q + j) * 1024 + o] = v[j];
    }
  }
}

// ---------------------------------------------------------------------------
extern "C" void kernel_launch(void* const* d_in, const int* in_sizes, int n_in,
                              void* d_out, int out_size, void* d_ws, size_t ws_size,
                              hipStream_t stream) {
  const float* X = (const float*)d_in[0];   // 4*4096*1024
  const float* W = (const float*)d_in[1];   // 1024*2048
  float* out = (float*)d_out;               // 4*4096*1024 fp32
  char* ws = (char*)d_ws;

  int G;
  if (ws_size >= 203489280ull)      G = 4;
  else if (ws_size >= 135299072ull) G = 2;
  else if (ws_size >= 104857600ull) G = 1;
  else return;
  const size_t PB = (size_t)G * 33554432ull;

  // layout (bytes):
  //   QK @ 0          (32MB)   bf16 [4][4096][1024]  (cols 0-511 Q, 512-1023 K)
  //   Vt @ 32MB       (32MB)   bf16 [4][1024][4096]
  //   P  @ 64MB       (PB)     bf16 TILED [G][16 ki][4096 q][256 k]
  //   Xb @ 64MB       (32MB)   aliases P (dead after k_qkv)
  //   Wbt@ 96MB       (4MB)    aliases P (dead after k_qkv)
  //   part @ 64MB+PB  (G*256KB) f32 [G][16][4096]
  //   linv @ +part    (G*16KB)  f32 [G][4096]
  u16* QK  = (u16*)(ws);
  u16* Vt  = (u16*)(ws + 33554432);
  u16* P   = (u16*)(ws + 67108864);
  u16* Xb  = (u16*)(ws + 67108864);
  u16* Wbt = (u16*)(ws + 100663296);
  float* part = (float*)(ws + 67108864 + PB);
  float* linv = (float*)(ws + 67108864 + PB + (size_t)G * 262144ull);

  k_cvt_x<<<dim3(8192), dim3(256), 0, stream>>>(X, Xb);
  k_cvt_w<<<dim3(32, 16), dim3(256), 0, stream>>>(W, Wbt);
  k_qkv<<<dim3(512), dim3(512), 0, stream>>>(Xb, Wbt, QK, Vt);
  for (int b0 = 0; b0 < 4; b0 += G) {
    int nwg_sp = 256 * G;
    k_sp<<<dim3(nwg_sp), dim3(512), 0, stream>>>(QK, P, part, b0, nwg_sp);
    k_finl<<<dim3(G * 16), dim3(256), 0, stream>>>(part, linv);
    k_scale<<<dim3(G * 2048), dim3(256), 0, stream>>>(Vt + (size_t)b0 * 4194304, linv);
    int nwg = 64 * G;
    k_pv<<<dim3(nwg), dim3(512), 0, stream>>>(P, Vt + (size_t)b0 * 4194304,
                                              out + (size_t)b0 * 4194304, nwg);
  }
}